// Round 1
// baseline (558.407 us; speedup 1.0000x reference)
//
#include <hip/hip_runtime.h>
#include <hip/hip_bf16.h>
#include <stdint.h>

// GateProj: silu((qx @ dequant(W)^T) * qxscale + bias)
// M=4096 K=4096 N=14336 G=128. W int4 packed 8/int32, low nibble first.
//
// Round 5: phase-split the K-loop (T3). Each BK=32 K-tile becomes 2 phases,
// each phase = {ds_read subtile + 1 half-stage issue -> barrier -> lgkmcnt(0)
// -> setprio(1) 16xMFMA setprio(0) -> barrier}. Same per-K=64 granularity as
// the m201 8-phase template. Counted vmcnt once per tile (8/4/0 edge chain),
// never 0 in steady state. 4-deep K-tile ring and swizzle unchanged
// (bank conflicts already 0).

#define M_DIM 4096
#define K_DIM 4096
#define N_DIM 14336
#define GSZ   128

typedef __bf16 bf16x8 __attribute__((ext_vector_type(8)));
typedef __bf16 bf16x4 __attribute__((ext_vector_type(4)));
typedef float  f32x4  __attribute__((ext_vector_type(4)));

#define GLOAD16(g, l) __builtin_amdgcn_global_load_lds( \
    (const __attribute__((address_space(1))) void*)(g), \
    (__attribute__((address_space(3))) void*)(l), 16, 0, 0)

#define WAITVM(N) asm volatile("s_waitcnt vmcnt(" #N ")" ::: "memory")
#define WAITLGKM0() asm volatile("s_waitcnt lgkmcnt(0)" ::: "memory")

// ---------------- prepass kernels ----------------

__global__ __launch_bounds__(256) void convertA_kernel(
    const float* __restrict__ qx, __bf16* __restrict__ out)
{
    const size_t i = ((size_t)blockIdx.x * 256 + threadIdx.x) * 8;
    const float4 a = *(const float4*)(qx + i);
    const float4 b = *(const float4*)(qx + i + 4);
    bf16x8 v;
    v[0] = (__bf16)a.x; v[1] = (__bf16)a.y; v[2] = (__bf16)a.z; v[3] = (__bf16)a.w;
    v[4] = (__bf16)b.x; v[5] = (__bf16)b.y; v[6] = (__bf16)b.z; v[7] = (__bf16)b.w;
    *(bf16x8*)(out + i) = v;
}

__global__ __launch_bounds__(256) void dequantW_kernel(
    const int* __restrict__ wq, const float* __restrict__ wscale,
    __bf16* __restrict__ out)
{
    const size_t g = (size_t)blockIdx.x * 256 + threadIdx.x;  // word index
    const int n  = (int)(g >> 9);                             // 512 words/row
    const int wi = (int)(g & 511);
    const float s = wscale[(size_t)n * (K_DIM / GSZ) + (wi >> 4)];
    const int w = wq[g];
    bf16x8 v;
    #pragma unroll
    for (int j = 0; j < 8; ++j) {
        const int q = ((int)((unsigned)w << (28 - 4 * j))) >> 28;
        v[j] = (__bf16)((float)q * s);
    }
    *(bf16x8*)(out + g * 8) = v;
}

// ---------------- main GEMM: 256^2 phase-split counted-vmcnt pipeline ------

constexpr int BM = 256, BN = 256, BK = 32;
constexpr int NT = K_DIM / BK;          // 128
constexpr int BUF_BYTES = 32768;        // A 16KB + B 16KB per K-tile

__global__ __launch_bounds__(512, 2) void gemm256_kernel(
    const __bf16* __restrict__ A,       // [M,K] bf16
    const __bf16* __restrict__ B,       // [N,K] bf16
    const float* __restrict__ qxscale,  // [M]
    const float* __restrict__ bias,     // [N]
    float* __restrict__ out)            // [M,N]
{
    __shared__ __align__(16) char smem[4 * BUF_BYTES];   // 128 KiB, 4-deep

    const int t    = threadIdx.x;
    const int lane = t & 63;
    const int wave = t >> 6;
    const int wr   = wave >> 2;   // 0..1 -> M half (128 rows)
    const int wc   = wave & 3;    // 0..3 -> N quarter (64 cols)

    // XCD-bijective swizzle: nwg=896 (16x56), 896%8==0, m-major within chunk
    const int bid = blockIdx.x;
    const int cpx = (M_DIM / BM) * (N_DIM / BN) / 8;   // 112
    const int wg  = (bid & 7) * cpx + (bid >> 3);
    const int tiles_n = N_DIM / BN;                    // 56
    const int tm = wg / tiles_n, tn = wg % tiles_n;
    const int m0 = tm * BM, n0 = tn * BN;

    // --- staging: thread t fills LDS bytes [s*8192 + t*16) per sweep s=0,1 ---
    // LDS linear slot: row = t>>2 (+s*128), phys colbyte = (t&3)*16.
    // Swizzle (64B stride): logical kb = phys ^ (((row>>1)&3)<<4) -> applied
    // to the GLOBAL source (rule 21). +128*s keeps row bits [2:1] -> one scb.
    const int srow = t >> 2;
    const int scb  = ((t & 3) * 16) ^ (((t >> 3) & 3) << 4);
    const char* aS = (const char*)A + (size_t)(m0 + srow) * K_DIM * 2 + scb;
    const char* bS = (const char*)B + (size_t)(n0 + srow) * K_DIM * 2 + scb;
    const size_t sweepG = (size_t)128 * K_DIM * 2;
    char* sbase = smem;

    auto STAGE_A = [&](int kt) {
        char* d = sbase + (kt & 3) * BUF_BYTES + t * 16;
        const char* s = aS + (size_t)kt * 64;
        GLOAD16(s, d);
        GLOAD16(s + sweepG, d + 8192);
    };
    auto STAGE_B = [&](int kt) {
        char* d = sbase + (kt & 3) * BUF_BYTES + 16384 + t * 16;
        const char* s = bS + (size_t)kt * 64;
        GLOAD16(s, d);
        GLOAD16(s + sweepG, d + 8192);
    };

    // --- ds_read addressing: addr = row*64 + (kb ^ (((row>>1)&3)<<4)) ---
    // row = R0 + (lane&15), R0 % 16 == 0 -> (row>>1)&3 == (lane>>1)&3.
    const int lane15 = lane & 15;
    const int pkb = ((lane >> 4) * 16) ^ (((lane >> 1) & 3) << 4);
    const int aRowB = (wr * 128 + lane15) * 64 + pkb;          // + mi*1024
    const int bRowB = (wc * 64 + lane15) * 64 + pkb + 16384;   // + ni*1024

    f32x4 acc[8][4] = {};

    // --- prologue: stage tiles 0,1,2; wait tile 0 landed (8 = tiles 1,2) ---
    STAGE_A(0); STAGE_B(0);
    STAGE_A(1); STAGE_B(1);
    STAGE_A(2); STAGE_B(2);
    WAITVM(8);
    __builtin_amdgcn_s_barrier();
    __builtin_amdgcn_sched_barrier(0);

    for (int kt = 0; kt < NT; ++kt) {
        const char* buf = sbase + (kt & 3) * BUF_BYTES;
        bf16x8 af[4], bf[4];

        // ================= phase 1: bf[0..3], af[0..3], stage A(kt+3) ======
        #pragma unroll
        for (int ni = 0; ni < 4; ++ni)
            bf[ni] = *(const bf16x8*)(buf + bRowB + ni * 1024);
        #pragma unroll
        for (int mi = 0; mi < 4; ++mi)
            af[mi] = *(const bf16x8*)(buf + aRowB + mi * 1024);

        // prefetch half-tile of kt+3 into buf[(kt+3)&3] (= kt-1's slot;
        // its reads were sealed two barriers ago)
        if (kt + 3 < NT) STAGE_A(kt + 3);

        __builtin_amdgcn_s_barrier();
        WAITLGKM0();
        __builtin_amdgcn_sched_barrier(0);
        __builtin_amdgcn_s_setprio(1);
        #pragma unroll
        for (int mi = 0; mi < 4; ++mi)
            #pragma unroll
            for (int ni = 0; ni < 4; ++ni)
                acc[mi][ni] = __builtin_amdgcn_mfma_f32_16x16x32_bf16(
                    af[mi], bf[ni], acc[mi][ni], 0, 0, 0);
        __builtin_amdgcn_s_setprio(0);
        __builtin_amdgcn_s_barrier();

        // ================= phase 2: af[4..7] (reuse bf), stage B(kt+3) =====
        #pragma unroll
        for (int mi = 0; mi < 4; ++mi)
            af[mi] = *(const bf16x8*)(buf + aRowB + (4 + mi) * 1024);

        if (kt + 3 < NT) STAGE_B(kt + 3);

        // counted vmcnt once per K-tile: tile kt+1 must be resident before
        // the next iteration's phase-1 reads. Steady state keeps tiles
        // kt+2,kt+3 (8 loads) in flight — never 0.
        if (kt + 1 < NT) {
            if (kt + 3 < NT)      WAITVM(8);
            else if (kt + 2 < NT) WAITVM(4);
            else                  WAITVM(0);
        }

        __builtin_amdgcn_s_barrier();
        WAITLGKM0();
        __builtin_amdgcn_sched_barrier(0);
        __builtin_amdgcn_s_setprio(1);
        #pragma unroll
        for (int mi = 0; mi < 4; ++mi)
            #pragma unroll
            for (int ni = 0; ni < 4; ++ni)
                acc[4 + mi][ni] = __builtin_amdgcn_mfma_f32_16x16x32_bf16(
                    af[mi], bf[ni], acc[4 + mi][ni], 0, 0, 0);
        __builtin_amdgcn_s_setprio(0);
        if (kt + 1 < NT) __builtin_amdgcn_s_barrier();
    }

    // ---- epilogue: y = acc*qxscale[m] + bias[n]; silu ----
    // D layout: col = lane&15 (n), row = (lane>>4)*4 + reg (m)
    const int c_col = lane & 15;
    const int c_r4  = (lane >> 4) * 4;
    #pragma unroll
    for (int mi = 0; mi < 8; ++mi) {
        const int mg = m0 + wr * 128 + mi * 16 + c_r4;
        float qs[4];
        #pragma unroll
        for (int r = 0; r < 4; ++r) qs[r] = qxscale[mg + r];
        #pragma unroll
        for (int ni = 0; ni < 4; ++ni) {
            const int ng = n0 + wc * 64 + ni * 16 + c_col;
            const float bv = bias[ng];
            #pragma unroll
            for (int r = 0; r < 4; ++r) {
                const float y = acc[mi][ni][r] * qs[r] + bv;
                out[(size_t)(mg + r) * N_DIM + ng] = y / (1.f + __expf(-y));
            }
        }
    }
}

// ---------------- fallback: round-1 fused kernel ----------------

constexpr int FBM = 128, FBN = 128, FBK = 64;
constexpr int FLDA = 72;

__global__ __launch_bounds__(256) void gateproj_fused_kernel(
    const float* __restrict__ qx, const float* __restrict__ qxscale,
    const int* __restrict__ wq, const float* __restrict__ wscale,
    const float* __restrict__ bias, float* __restrict__ out)
{
    __shared__ __bf16 sA[FBM * FLDA];
    __shared__ __bf16 sB[FBN * FLDA];

    const int tid  = threadIdx.x;
    const int lane = tid & 63;
    const int wave = tid >> 6;
    const int wm = wave >> 1, wn = wave & 1;

    const int bid = blockIdx.x;
    const int cpx = (M_DIM / FBM) * (N_DIM / FBN) / 8;
    const int wg  = (bid & 7) * cpx + (bid >> 3);
    const int tiles_n = N_DIM / FBN;
    const int tm = wg / tiles_n, tn = wg % tiles_n;
    const int m0 = tm * FBM, n0 = tn * FBN;

    const int a_row = tid >> 4;
    const int a_col = (tid & 15) * 4;
    const float* aPtr = qx + (size_t)(m0 + a_row) * K_DIM + a_col;

    const int b_row = tid >> 1;
    const int b_wb  = (tid & 1) * 4;
    const int*   bPtr = wq     + (size_t)(n0 + b_row) * (K_DIM / 8) + b_wb;
    const float* sPtr = wscale + (size_t)(n0 + b_row) * (K_DIM / GSZ);

    float4 aReg[8];
    int    bRegW[4];
    float  bScl;
    f32x4 acc[4][4] = {};

    auto LOAD = [&](int kt) {
        const float* ap = aPtr + kt * FBK;
        #pragma unroll
        for (int i = 0; i < 8; ++i)
            aReg[i] = *(const float4*)(ap + (size_t)i * 16 * K_DIM);
        int4 b = *(const int4*)(bPtr + kt * 8);
        bRegW[0] = b.x; bRegW[1] = b.y; bRegW[2] = b.z; bRegW[3] = b.w;
        bScl = sPtr[kt >> 1];
    };

    auto STORE = [&]() {
        #pragma unroll
        for (int i = 0; i < 8; ++i) {
            bf16x4 v;
            v[0] = (__bf16)aReg[i].x; v[1] = (__bf16)aReg[i].y;
            v[2] = (__bf16)aReg[i].z; v[3] = (__bf16)aReg[i].w;
            *(bf16x4*)&sA[(a_row + i * 16) * FLDA + a_col] = v;
        }
        const int cb = (tid & 1) * 32;
        #pragma unroll
        for (int wi = 0; wi < 4; ++wi) {
            const int w = bRegW[wi];
            bf16x8 o;
            #pragma unroll
            for (int j = 0; j < 8; ++j) {
                const int v = ((int)((unsigned)w << (28 - 4 * j))) >> 28;
                o[j] = (__bf16)((float)v * bScl);
            }
            *(bf16x8*)&sB[b_row * FLDA + cb + wi * 8] = o;
        }
    };

    LOAD(0); STORE(); __syncthreads();

    const int FNT = K_DIM / FBK;
    for (int kt = 0; kt < FNT; ++kt) {
        if (kt + 1 < FNT) LOAD(kt + 1);
        #pragma unroll
        for (int kk = 0; kk < 2; ++kk) {
            bf16x8 af[4], bfr[4];
            const int ko = kk * 32 + (lane >> 4) * 8;
            #pragma unroll
            for (int mi = 0; mi < 4; ++mi)
                af[mi] = *(const bf16x8*)&sA[(wm * 64 + mi * 16 + (lane & 15)) * FLDA + ko];
            #pragma unroll
            for (int ni = 0; ni < 4; ++ni)
                bfr[ni] = *(const bf16x8*)&sB[(wn * 64 + ni * 16 + (lane & 15)) * FLDA + ko];
            #pragma unroll
            for (int mi = 0; mi < 4; ++mi)
                #pragma unroll
                for (int ni = 0; ni < 4; ++ni)
                    acc[mi][ni] = __builtin_amdgcn_mfma_f32_16x16x32_bf16(
                        af[mi], bfr[ni], acc[mi][ni], 0, 0, 0);
        }
        __syncthreads();
        if (kt + 1 < FNT) { STORE(); __syncthreads(); }
    }

    const int c_col = lane & 15;
    const int c_r4  = (lane >> 4) * 4;
    #pragma unroll
    for (int mi = 0; mi < 4; ++mi) {
        const int mg = m0 + wm * 64 + mi * 16 + c_r4;
        float qs[4];
        #pragma unroll
        for (int r = 0; r < 4; ++r) qs[r] = qxscale[mg + r];
        #pragma unroll
        for (int ni = 0; ni < 4; ++ni) {
            const int ng = n0 + wn * 64 + ni * 16 + c_col;
            const float bv = bias[ng];
            #pragma unroll
            for (int r = 0; r < 4; ++r) {
                const float y = acc[mi][ni][r] * qs[r] + bv;
                out[(size_t)(mg + r) * N_DIM + ng] = y / (1.f + __expf(-y));
            }
        }
    }
}

// ---------------- launch ----------------

extern "C" void kernel_launch(void* const* d_in, const int* in_sizes, int n_in,
                              void* d_out, int out_size, void* d_ws, size_t ws_size,
                              hipStream_t stream) {
    const float* qx      = (const float*)d_in[0];
    const float* qxscale = (const float*)d_in[1];
    const int*   wq      = (const int*)d_in[2];
    const float* wscale  = (const float*)d_in[3];
    const float* bias    = (const float*)d_in[4];
    float* out = (float*)d_out;

    const size_t needA = (size_t)M_DIM * K_DIM * 2;
    const size_t needW = (size_t)N_DIM * K_DIM * 2;

    if (ws_size >= needA + needW) {
        __bf16* Abf = (__bf16*)d_ws;
        __bf16* Wbf = Abf + (size_t)M_DIM * K_DIM;

        hipLaunchKernelGGL(convertA_kernel, dim3(M_DIM * K_DIM / 8 / 256), dim3(256),
                           0, stream, qx, Abf);
        hipLaunchKernelGGL(dequantW_kernel, dim3(N_DIM * (K_DIM / 8) / 256), dim3(256),
                           0, stream, wq, wscale, Wbf);

        const int grid = (M_DIM / BM) * (N_DIM / BN);   // 896
        hipLaunchKernelGGL(gemm256_kernel, dim3(grid), dim3(512), 0, stream,
                           Abf, Wbf, qxscale, bias, out);
    } else {
        const int grid = (M_DIM / FBM) * (N_DIM / FBN);
        hipLaunchKernelGGL(gateproj_fused_kernel, dim3(grid), dim3(256), 0, stream,
                           qx, qxscale, wq, wscale, bias, out);
    }
}

// Round 2
// 502.824 us; speedup vs baseline: 1.1105x; 1.1105x over previous
//
#include <hip/hip_runtime.h>
#include <hip/hip_bf16.h>
#include <stdint.h>

// GateProj: silu((qx @ dequant(W)^T) * qxscale + bias)
// M=4096 K=4096 N=14336 G=128. W int4 packed 8/int32, low nibble first.
//
// Round 6: faithful m201 8-phase port. BK=64, 2 K-tiles/iter, 8 phases/iter,
// 16 MFMA per phase by C-quadrant rotation, 2 gload_lds (quarter-tile sweeps)
// per phase, vmcnt(6) only before ph4/ph8 barriers (3 sweeps in flight).
// 2x64KB LDS buffers (even/odd K-tiles). Swizzle: granule ^= row&7 within
// 128B rows (2-way max = free), linear LDS dest + inverse-swizzled global
// source + swizzled ds_read.

#define M_DIM 4096
#define K_DIM 4096
#define N_DIM 14336
#define GSZ   128

typedef __bf16 bf16x8 __attribute__((ext_vector_type(8)));
typedef __bf16 bf16x4 __attribute__((ext_vector_type(4)));
typedef float  f32x4  __attribute__((ext_vector_type(4)));

#define GLOAD16(g, l) __builtin_amdgcn_global_load_lds( \
    (const __attribute__((address_space(1))) void*)(g), \
    (__attribute__((address_space(3))) void*)(l), 16, 0, 0)

#define WAITVM(N) asm volatile("s_waitcnt vmcnt(" #N ")" ::: "memory")
#define WAITLGKM0() asm volatile("s_waitcnt lgkmcnt(0)" ::: "memory")

// ---------------- prepass kernels ----------------

__global__ __launch_bounds__(256) void convertA_kernel(
    const float* __restrict__ qx, __bf16* __restrict__ out)
{
    const size_t i = ((size_t)blockIdx.x * 256 + threadIdx.x) * 8;
    const float4 a = *(const float4*)(qx + i);
    const float4 b = *(const float4*)(qx + i + 4);
    bf16x8 v;
    v[0] = (__bf16)a.x; v[1] = (__bf16)a.y; v[2] = (__bf16)a.z; v[3] = (__bf16)a.w;
    v[4] = (__bf16)b.x; v[5] = (__bf16)b.y; v[6] = (__bf16)b.z; v[7] = (__bf16)b.w;
    *(bf16x8*)(out + i) = v;
}

__global__ __launch_bounds__(256) void dequantW_kernel(
    const int* __restrict__ wq, const float* __restrict__ wscale,
    __bf16* __restrict__ out)
{
    const size_t g = (size_t)blockIdx.x * 256 + threadIdx.x;  // word index
    const int n  = (int)(g >> 9);                             // 512 words/row
    const int wi = (int)(g & 511);
    const float s = wscale[(size_t)n * (K_DIM / GSZ) + (wi >> 4)];
    const int w = wq[g];
    bf16x8 v;
    #pragma unroll
    for (int j = 0; j < 8; ++j) {
        const int q = ((int)((unsigned)w << (28 - 4 * j))) >> 28;
        v[j] = (__bf16)((float)q * s);
    }
    *(bf16x8*)(out + g * 8) = v;
}

// ---------------- main GEMM: 256^2 m201-style 8-phase pipeline ----------------

constexpr int BM = 256, BN = 256, BK = 64;
constexpr int NT  = K_DIM / BK;         // 64 K-tiles
constexpr int NIT = NT / 2;             // 32 iterations (2 tiles/iter)
constexpr int BUF_BYTES = 65536;        // A 32KB + B 32KB per K-tile

__global__ __launch_bounds__(512, 2) void gemm256_kernel(
    const __bf16* __restrict__ A,       // [M,K] bf16
    const __bf16* __restrict__ B,       // [N,K] bf16
    const float* __restrict__ qxscale,  // [M]
    const float* __restrict__ bias,     // [N]
    float* __restrict__ out)            // [M,N]
{
    __shared__ __align__(16) char smem[2 * BUF_BYTES];   // 128 KiB

    const int t    = threadIdx.x;
    const int lane = t & 63;
    const int wave = t >> 6;
    const int wr   = wave >> 2;   // 0..1 -> M half (128 rows)
    const int wc   = wave & 3;    // 0..3 -> N quarter (64 cols)

    // XCD-bijective swizzle: nwg=896 (16x56), 896%8==0, m-major within chunk
    const int bid = blockIdx.x;
    const int cpx = (M_DIM / BM) * (N_DIM / BN) / 8;   // 112
    const int wg  = (bid & 7) * cpx + (bid >> 3);
    const int tiles_n = N_DIM / BN;                    // 56
    const int tm = wg / tiles_n, tn = wg % tiles_n;
    const int m0 = tm * BM, n0 = tn * BN;

    // --- staging: one sweep = 512 thr x 16B = 8KB = 64 rows x 128B.
    // Quarter q of a tile = rows [q*64, q*64+64). Thread t: row srow=t>>3,
    // phys granule t&7; LDS dest linear = q*8192 + t*16; global source
    // granule = (t&7) ^ (srow&7) (involution; rule 21).
    const int srow = t >> 3;
    const int sg16 = (((t & 7) ^ (srow & 7)) << 4);
    const size_t KB = (size_t)K_DIM * 2;               // 8192 bytes/row
    const char* aS = (const char*)A + (size_t)(m0 + srow) * KB + sg16;
    const char* bS = (const char*)B + (size_t)(n0 + srow) * KB + sg16;
    char* sbase = smem;

    auto STAGE_AQ = [&](int tile, int q) {
        GLOAD16(aS + (size_t)tile * 128 + (size_t)q * 64 * KB,
                sbase + (tile & 1) * BUF_BYTES + q * 8192 + t * 16);
    };
    auto STAGE_BQ = [&](int tile, int q) {
        GLOAD16(bS + (size_t)tile * 128 + (size_t)q * 64 * KB,
                sbase + (tile & 1) * BUF_BYTES + 32768 + q * 8192 + t * 16);
    };

    // --- ds_read: row = base + lane15, logical granule c = kk*4 + (lane>>4),
    // phys byte col = ((c ^ (row&7)) << 4); row&7 == lane15&7.
    const int lane15 = lane & 15;
    const int lc     = lane >> 4;                        // 0..3
    const int swzc   = ((lc ^ (lane15 & 7)) << 4);       // kk=0 column byte
    const int aR0 = (wr * 128 + lane15) * 128 + swzc;    // + mi*2048
    const int aR1 = aR0 ^ 64;                            // kk=1
    const int bR0 = 32768 + (wc * 64 + lane15) * 128 + swzc;  // + ni*2048
    const int bR1 = bR0 ^ 64;

    f32x4 acc[8][4] = {};
    bf16x8 af[4][2], bfl[2][2], bfh[2][2];

    auto DS_AF = [&](const char* buf, int mibase) {
        #pragma unroll
        for (int mi = 0; mi < 4; ++mi) {
            af[mi][0] = *(const bf16x8*)(buf + aR0 + (mibase + mi) * 2048);
            af[mi][1] = *(const bf16x8*)(buf + aR1 + (mibase + mi) * 2048);
        }
    };
    auto DS_BL = [&](const char* buf) {
        #pragma unroll
        for (int ni = 0; ni < 2; ++ni) {
            bfl[ni][0] = *(const bf16x8*)(buf + bR0 + ni * 2048);
            bfl[ni][1] = *(const bf16x8*)(buf + bR1 + ni * 2048);
        }
    };
    auto DS_BH = [&](const char* buf) {
        #pragma unroll
        for (int ni = 0; ni < 2; ++ni) {
            bfh[ni][0] = *(const bf16x8*)(buf + bR0 + (2 + ni) * 2048);
            bfh[ni][1] = *(const bf16x8*)(buf + bR1 + (2 + ni) * 2048);
        }
    };
    auto MFMAQ_L = [&](int mo) {   // quadrant vs bf-lo (ni 0..1)
        #pragma unroll
        for (int kk = 0; kk < 2; ++kk)
            #pragma unroll
            for (int mi = 0; mi < 4; ++mi)
                #pragma unroll
                for (int ni = 0; ni < 2; ++ni)
                    acc[mo + mi][ni] = __builtin_amdgcn_mfma_f32_16x16x32_bf16(
                        af[mi][kk], bfl[ni][kk], acc[mo + mi][ni], 0, 0, 0);
    };
    auto MFMAQ_H = [&](int mo) {   // quadrant vs bf-hi (ni 2..3)
        #pragma unroll
        for (int kk = 0; kk < 2; ++kk)
            #pragma unroll
            for (int mi = 0; mi < 4; ++mi)
                #pragma unroll
                for (int ni = 0; ni < 2; ++ni)
                    acc[mo + mi][2 + ni] = __builtin_amdgcn_mfma_f32_16x16x32_bf16(
                        af[mi][kk], bfh[ni][kk], acc[mo + mi][2 + ni], 0, 0, 0);
    };

    #define PH_SYNC() do { __builtin_amdgcn_s_barrier(); WAITLGKM0(); \
        __builtin_amdgcn_sched_barrier(0); __builtin_amdgcn_s_setprio(1); } while (0)
    #define PH_END() do { __builtin_amdgcn_s_setprio(0); \
        __builtin_amdgcn_s_barrier(); } while (0)

    // --- prologue: tile0 fully (8 sweeps), tile1 Aq0,Aq2,Bq0-3 (6 sweeps).
    // vmcnt(6) -> tile0 resident; barrier publishes block-wide.
    #pragma unroll
    for (int q = 0; q < 4; ++q) STAGE_AQ(0, q);
    #pragma unroll
    for (int q = 0; q < 4; ++q) STAGE_BQ(0, q);
    STAGE_AQ(1, 0); STAGE_AQ(1, 2);
    #pragma unroll
    for (int q = 0; q < 4; ++q) STAGE_BQ(1, q);
    WAITVM(6);
    __builtin_amdgcn_s_barrier();
    __builtin_amdgcn_sched_barrier(0);

    for (int i = 0; i < NIT; ++i) {
        const int t0 = 2 * i, t1 = 2 * i + 1;
        const bool more = (i + 1 < NIT);
        const char* bufE = sbase;               // even tile t0
        const char* bufO = sbase + BUF_BYTES;   // odd tile t1

        // ===== tile t0 (bufE) =====
        // ph1: reads af-lo + bf-lo; stage t1's A q1,q3 (freed by prev ph7)
        DS_AF(bufE, 0); DS_BL(bufE);
        STAGE_AQ(t1, 1); STAGE_AQ(t1, 3);
        PH_SYNC(); MFMAQ_L(0); PH_END();

        // ph2: reads bf-hi; stage (t0+2) A q0,q2 (freed by ph1)
        DS_BH(bufE);
        if (more) { STAGE_AQ(t0 + 2, 0); STAGE_AQ(t0 + 2, 2); }
        PH_SYNC(); MFMAQ_H(0); PH_END();

        // ph3: reads af-hi; stage (t0+2) B q0,q1 (freed by ph2)
        DS_AF(bufE, 4);
        if (more) { STAGE_BQ(t0 + 2, 0); STAGE_BQ(t0 + 2, 1); }
        PH_SYNC(); MFMAQ_H(4); PH_END();

        // ph4: no reads; stage (t0+2) B q2,q3; vmcnt -> tile t1 resident
        if (more) { STAGE_BQ(t0 + 2, 2); STAGE_BQ(t0 + 2, 3); WAITVM(6); }
        else      { WAITVM(0); }
        __builtin_amdgcn_s_barrier();
        __builtin_amdgcn_sched_barrier(0);
        __builtin_amdgcn_s_setprio(1);
        MFMAQ_L(4);
        PH_END();

        // ===== tile t1 (bufO) =====
        // ph5: reads af-lo + bf-lo; stage (t0+2) A q1,q3 (freed by ph3)
        DS_AF(bufO, 0); DS_BL(bufO);
        if (more) { STAGE_AQ(t0 + 2, 1); STAGE_AQ(t0 + 2, 3); }
        PH_SYNC(); MFMAQ_L(0); PH_END();

        // ph6: reads bf-hi; stage (t1+2) A q0,q2 (freed by ph5)
        DS_BH(bufO);
        if (more) { STAGE_AQ(t1 + 2, 0); STAGE_AQ(t1 + 2, 2); }
        PH_SYNC(); MFMAQ_H(0); PH_END();

        // ph7: reads af-hi; stage (t1+2) B q0,q1 (freed by ph6)
        DS_AF(bufO, 4);
        if (more) { STAGE_BQ(t1 + 2, 0); STAGE_BQ(t1 + 2, 1); }
        PH_SYNC(); MFMAQ_H(4); PH_END();

        // ph8: no reads; stage (t1+2) B q2,q3; vmcnt -> tile t0+2 resident
        if (more) { STAGE_BQ(t1 + 2, 2); STAGE_BQ(t1 + 2, 3); WAITVM(6); }
        __builtin_amdgcn_s_barrier();
        __builtin_amdgcn_sched_barrier(0);
        __builtin_amdgcn_s_setprio(1);
        MFMAQ_L(4);
        PH_END();
    }

    #undef PH_SYNC
    #undef PH_END

    // ---- epilogue: y = acc*qxscale[m] + bias[n]; silu ----
    // D layout: col = lane&15 (n), row = (lane>>4)*4 + reg (m)
    const int c_col = lane & 15;
    const int c_r4  = (lane >> 4) * 4;
    #pragma unroll
    for (int mi = 0; mi < 8; ++mi) {
        const int mg = m0 + wr * 128 + mi * 16 + c_r4;
        float qs[4];
        #pragma unroll
        for (int r = 0; r < 4; ++r) qs[r] = qxscale[mg + r];
        #pragma unroll
        for (int ni = 0; ni < 4; ++ni) {
            const int ng = n0 + wc * 64 + ni * 16 + c_col;
            const float bv = bias[ng];
            #pragma unroll
            for (int r = 0; r < 4; ++r) {
                const float y = acc[mi][ni][r] * qs[r] + bv;
                out[(size_t)(mg + r) * N_DIM + ng] = y / (1.f + __expf(-y));
            }
        }
    }
}

// ---------------- fallback: round-1 fused kernel ----------------

constexpr int FBM = 128, FBN = 128, FBK = 64;
constexpr int FLDA = 72;

__global__ __launch_bounds__(256) void gateproj_fused_kernel(
    const float* __restrict__ qx, const float* __restrict__ qxscale,
    const int* __restrict__ wq, const float* __restrict__ wscale,
    const float* __restrict__ bias, float* __restrict__ out)
{
    __shared__ __bf16 sA[FBM * FLDA];
    __shared__ __bf16 sB[FBN * FLDA];

    const int tid  = threadIdx.x;
    const int lane = tid & 63;
    const int wave = tid >> 6;
    const int wm = wave >> 1, wn = wave & 1;

    const int bid = blockIdx.x;
    const int cpx = (M_DIM / FBM) * (N_DIM / FBN) / 8;
    const int wg  = (bid & 7) * cpx + (bid >> 3);
    const int tiles_n = N_DIM / FBN;
    const int tm = wg / tiles_n, tn = wg % tiles_n;
    const int m0 = tm * FBM, n0 = tn * FBN;

    const int a_row = tid >> 4;
    const int a_col = (tid & 15) * 4;
    const float* aPtr = qx + (size_t)(m0 + a_row) * K_DIM + a_col;

    const int b_row = tid >> 1;
    const int b_wb  = (tid & 1) * 4;
    const int*   bPtr = wq     + (size_t)(n0 + b_row) * (K_DIM / 8) + b_wb;
    const float* sPtr = wscale + (size_t)(n0 + b_row) * (K_DIM / GSZ);

    float4 aReg[8];
    int    bRegW[4];
    float  bScl;
    f32x4 acc[4][4] = {};

    auto LOAD = [&](int kt) {
        const float* ap = aPtr + kt * FBK;
        #pragma unroll
        for (int i = 0; i < 8; ++i)
            aReg[i] = *(const float4*)(ap + (size_t)i * 16 * K_DIM);
        int4 b = *(const int4*)(bPtr + kt * 8);
        bRegW[0] = b.x; bRegW[1] = b.y; bRegW[2] = b.z; bRegW[3] = b.w;
        bScl = sPtr[kt >> 1];
    };

    auto STORE = [&]() {
        #pragma unroll
        for (int i = 0; i < 8; ++i) {
            bf16x4 v;
            v[0] = (__bf16)aReg[i].x; v[1] = (__bf16)aReg[i].y;
            v[2] = (__bf16)aReg[i].z; v[3] = (__bf16)aReg[i].w;
            *(bf16x4*)&sA[(a_row + i * 16) * FLDA + a_col] = v;
        }
        const int cb = (tid & 1) * 32;
        #pragma unroll
        for (int wi = 0; wi < 4; ++wi) {
            const int w = bRegW[wi];
            bf16x8 o;
            #pragma unroll
            for (int j = 0; j < 8; ++j) {
                const int v = ((int)((unsigned)w << (28 - 4 * j))) >> 28;
                o[j] = (__bf16)((float)v * bScl);
            }
            *(bf16x8*)&sB[b_row * FLDA + cb + wi * 8] = o;
        }
    };

    LOAD(0); STORE(); __syncthreads();

    const int FNT = K_DIM / FBK;
    for (int kt = 0; kt < FNT; ++kt) {
        if (kt + 1 < FNT) LOAD(kt + 1);
        #pragma unroll
        for (int kk = 0; kk < 2; ++kk) {
            bf16x8 af[4], bfr[4];
            const int ko = kk * 32 + (lane >> 4) * 8;
            #pragma unroll
            for (int mi = 0; mi < 4; ++mi)
                af[mi] = *(const bf16x8*)&sA[(wm * 64 + mi * 16 + (lane & 15)) * FLDA + ko];
            #pragma unroll
            for (int ni = 0; ni < 4; ++ni)
                bfr[ni] = *(const bf16x8*)&sB[(wn * 64 + ni * 16 + (lane & 15)) * FLDA + ko];
            #pragma unroll
            for (int mi = 0; mi < 4; ++mi)
                #pragma unroll
                for (int ni = 0; ni < 4; ++ni)
                    acc[mi][ni] = __builtin_amdgcn_mfma_f32_16x16x32_bf16(
                        af[mi], bfr[ni], acc[mi][ni], 0, 0, 0);
        }
        __syncthreads();
        if (kt + 1 < FNT) { STORE(); __syncthreads(); }
    }

    const int c_col = lane & 15;
    const int c_r4  = (lane >> 4) * 4;
    #pragma unroll
    for (int mi = 0; mi < 4; ++mi) {
        const int mg = m0 + wm * 64 + mi * 16 + c_r4;
        float qs[4];
        #pragma unroll
        for (int r = 0; r < 4; ++r) qs[r] = qxscale[mg + r];
        #pragma unroll
        for (int ni = 0; ni < 4; ++ni) {
            const int ng = n0 + wn * 64 + ni * 16 + c_col;
            const float bv = bias[ng];
            #pragma unroll
            for (int r = 0; r < 4; ++r) {
                const float y = acc[mi][ni][r] * qs[r] + bv;
                out[(size_t)(mg + r) * N_DIM + ng] = y / (1.f + __expf(-y));
            }
        }
    }
}

// ---------------- launch ----------------

extern "C" void kernel_launch(void* const* d_in, const int* in_sizes, int n_in,
                              void* d_out, int out_size, void* d_ws, size_t ws_size,
                              hipStream_t stream) {
    const float* qx      = (const float*)d_in[0];
    const float* qxscale = (const float*)d_in[1];
    const int*   wq      = (const int*)d_in[2];
    const float* wscale  = (const float*)d_in[3];
    const float* bias    = (const float*)d_in[4];
    float* out = (float*)d_out;

    const size_t needA = (size_t)M_DIM * K_DIM * 2;
    const size_t needW = (size_t)N_DIM * K_DIM * 2;

    if (ws_size >= needA + needW) {
        __bf16* Abf = (__bf16*)d_ws;
        __bf16* Wbf = Abf + (size_t)M_DIM * K_DIM;

        hipLaunchKernelGGL(convertA_kernel, dim3(M_DIM * K_DIM / 8 / 256), dim3(256),
                           0, stream, qx, Abf);
        hipLaunchKernelGGL(dequantW_kernel, dim3(N_DIM * (K_DIM / 8) / 256), dim3(256),
                           0, stream, wq, wscale, Wbf);

        const int grid = (M_DIM / BM) * (N_DIM / BN);   // 896
        hipLaunchKernelGGL(gemm256_kernel, dim3(grid), dim3(512), 0, stream,
                           Abf, Wbf, qxscale, bias, out);
    } else {
        const int grid = (M_DIM / FBM) * (N_DIM / FBN);
        hipLaunchKernelGGL(gateproj_fused_kernel, dim3(grid), dim3(256), 0, stream,
                           qx, qxscale, wq, wscale, bias, out);
    }
}